// Round 3
// baseline (287.105 us; speedup 1.0000x reference)
//
#include <hip/hip_runtime.h>

#define NN 50000
#define NE 800000

// ---- bf16 helpers (manual, f32 accumulate everywhere) ----
__device__ __forceinline__ float lof(unsigned v) { return __uint_as_float(v << 16); }
__device__ __forceinline__ float hif(unsigned v) { return __uint_as_float(v & 0xffff0000u); }
__device__ __forceinline__ unsigned bf16rne(float f) {
    unsigned u = __float_as_uint(f);
    return (u + 0x7fffu + ((u >> 16) & 1u)) >> 16;
}
__device__ __forceinline__ unsigned pack2(float a, float b) {
    return bf16rne(a) | (bf16rne(b) << 16);
}

// ---------------- GEMM1 (+fused edge histogram): H1[50000,128](bf16) = x @ W1 ----------------
// 3125 blocks x 256 threads = exactly NE threads -> each also counts one edge.
__global__ __launch_bounds__(256) void gemm1_k(const float* __restrict__ x,
                                               const float* __restrict__ W,
                                               uint2* __restrict__ H1,
                                               const int* __restrict__ dst,
                                               int* __restrict__ count) {
    __shared__ float wl[128 * 128];   // whole W1, 64 KB
    __shared__ float xl[16 * 128];
    const int tid = threadIdx.x;

    // fused histogram: one edge per thread
    atomicAdd(&count[dst[blockIdx.x * 256 + tid]], 1);

    const float4* W4 = (const float4*)W;
    float4* wl4 = (float4*)wl;
#pragma unroll
    for (int i = 0; i < 16; ++i) wl4[tid + 256 * i] = W4[tid + 256 * i];

    const long row0 = (long)blockIdx.x * 16;
    const float4* x4 = (const float4*)(x + row0 * 128);
    float4* xl4 = (float4*)xl;
#pragma unroll
    for (int i = 0; i < 2; ++i) xl4[tid + 256 * i] = x4[tid + 256 * i];
    __syncthreads();

    const int q = tid & 31;    // 4-channel group
    const int rg = tid >> 5;   // rows rg, rg+8
    float4 acc0 = {0.f, 0.f, 0.f, 0.f};
    float4 acc1 = {0.f, 0.f, 0.f, 0.f};
    for (int k = 0; k < 128; ++k) {
        float4 w = wl4[k * 32 + q];
        float a0 = xl[rg * 128 + k];
        float a1 = xl[(rg + 8) * 128 + k];
        acc0.x += a0 * w.x; acc0.y += a0 * w.y; acc0.z += a0 * w.z; acc0.w += a0 * w.w;
        acc1.x += a1 * w.x; acc1.y += a1 * w.y; acc1.z += a1 * w.z; acc1.w += a1 * w.w;
    }
    uint2* out2 = H1 + row0 * 32;
    out2[rg * 32 + q]       = make_uint2(pack2(acc0.x, acc0.y), pack2(acc0.z, acc0.w));
    out2[(rg + 8) * 32 + q] = make_uint2(pack2(acc1.x, acc1.y), pack2(acc1.z, acc1.w));
}

// ---------------- single-block exclusive scan: count[NN] -> rowoff[NN+1] ----------------
#define SCAN_C 49   // 1024*49 = 50176 >= NN
__global__ __launch_bounds__(1024) void scan_k(const int* __restrict__ count,
                                               int* __restrict__ rowoff) {
    __shared__ int sm[1024];
    const int t = threadIdx.x;
    const int base = t * SCAN_C;
    int s = 0;
#pragma unroll
    for (int i = 0; i < SCAN_C; ++i) {
        const int idx = base + i;
        if (idx < NN) s += count[idx];
    }
    sm[t] = s;
    __syncthreads();
#pragma unroll
    for (int off = 1; off < 1024; off <<= 1) {
        int u = (t >= off) ? sm[t - off] : 0;
        __syncthreads();
        sm[t] += u;
        __syncthreads();
    }
    int run = sm[t] - s;   // exclusive prefix of this thread's chunk
    for (int i = 0; i < SCAN_C; ++i) {
        const int idx = base + i;
        if (idx < NN) { rowoff[idx] = run; run += count[idx]; }
    }
    if (t == 0) rowoff[NN] = NE;
}

__global__ __launch_bounds__(256) void fill_k(const int* __restrict__ src,
                                              const int* __restrict__ dst,
                                              const int* __restrict__ rowoff,
                                              int* __restrict__ cursor,
                                              int* __restrict__ eid) {
    const int e = blockIdx.x * 256 + threadIdx.x;
    const int d = dst[e];
    const int p = atomicAdd(&cursor[d], 1);
    eid[rowoff[d] + p] = src[e];
}

// ---------------- gather1 + bias + relu: h[n](f32) = relu(sum H1bf16[j] + b1) ----------------
// one wave per node; lane owns 2 channels (one packed uint)
__global__ __launch_bounds__(256) void gather1_k(const unsigned* __restrict__ H1,
                                                 const int* __restrict__ rowoff,
                                                 const int* __restrict__ eid,
                                                 const float* __restrict__ b1,
                                                 float2* __restrict__ h) {
    const int n = blockIdx.x * 4 + (threadIdx.x >> 6);
    const int lane = threadIdx.x & 63;
    const int beg = rowoff[n], end = rowoff[n + 1];
    float ax = 0.f, ay = 0.f;
    int k = beg;
    for (; k + 3 < end; k += 4) {
        const int s0 = eid[k], s1 = eid[k + 1], s2 = eid[k + 2], s3 = eid[k + 3];
        const unsigned v0 = H1[s0 * 64 + lane];
        const unsigned v1 = H1[s1 * 64 + lane];
        const unsigned v2 = H1[s2 * 64 + lane];
        const unsigned v3 = H1[s3 * 64 + lane];
        ax += (lof(v0) + lof(v1)) + (lof(v2) + lof(v3));
        ay += (hif(v0) + hif(v1)) + (hif(v2) + hif(v3));
    }
    for (; k < end; ++k) {
        const unsigned v = H1[eid[k] * 64 + lane];
        ax += lof(v); ay += hif(v);
    }
    const float2 b = ((const float2*)b1)[lane];
    float2 o;
    o.x = fmaxf(ax + b.x, 0.f);
    o.y = fmaxf(ay + b.y, 0.f);
    h[n * 64 + lane] = o;
}

// ---------------- GEMM2: H2[50000,40](bf16) = h(f32) @ W2 ----------------
__global__ __launch_bounds__(256) void gemm2_k(const float* __restrict__ h,
                                               const float* __restrict__ W2,
                                               unsigned short* __restrict__ H2) {
    __shared__ float wl[128 * 40];
    const int tid = threadIdx.x;
    for (int i = tid; i < 128 * 40 / 4; i += 256)
        ((float4*)wl)[i] = ((const float4*)W2)[i];
    __syncthreads();

    const int i = blockIdx.x * 256 + tid;
    if (i >= NN * 40) return;
    const int row = i / 40;
    const int c = i - row * 40;
    const float4* hrow = (const float4*)(h + (long)row * 128);
    float acc = 0.f;
#pragma unroll
    for (int k4 = 0; k4 < 32; ++k4) {
        float4 hv = hrow[k4];
        acc += hv.x * wl[(k4 * 4 + 0) * 40 + c];
        acc += hv.y * wl[(k4 * 4 + 1) * 40 + c];
        acc += hv.z * wl[(k4 * 4 + 2) * 40 + c];
        acc += hv.w * wl[(k4 * 4 + 3) * 40 + c];
    }
    H2[i] = (unsigned short)bf16rne(acc);
}

// ---------------- gather2 + bias + log_softmax ----------------
// one wave per node; 3 edge-groups x 20 lanes, each lane = 2 channels (packed uint)
__global__ __launch_bounds__(256) void gather2_k(const unsigned* __restrict__ H2,
                                                 const int* __restrict__ rowoff,
                                                 const int* __restrict__ eid,
                                                 const float* __restrict__ b2,
                                                 float* __restrict__ out) {
    const int n = blockIdx.x * 4 + (threadIdx.x >> 6);
    const int lane = threadIdx.x & 63;
    const int g = lane / 20;        // edge-group 0..2 (g==3 idle)
    const int c2 = lane - g * 20;   // channel-pair 0..19
    const int beg = rowoff[n], end = rowoff[n + 1];
    float ax = 0.f, ay = 0.f;
    if (g < 3) {
        int k = beg + g;
        for (; k + 3 < end; k += 6) {   // 2 edges per group per iter
            const int s0 = eid[k], s1 = eid[k + 3];
            const unsigned v0 = H2[s0 * 20 + c2];
            const unsigned v1 = H2[s1 * 20 + c2];
            ax += lof(v0) + lof(v1);
            ay += hif(v0) + hif(v1);
        }
        if (k < end) {
            const unsigned v = H2[eid[k] * 20 + c2];
            ax += lof(v); ay += hif(v);
        }
    }
    // combine the 3 groups: lanes 0..19 accumulate lanes +20, +40
    ax += __shfl(ax, lane + 20, 64) + __shfl(ax, lane + 40, 64);
    ay += __shfl(ay, lane + 20, 64) + __shfl(ay, lane + 40, 64);

    const bool act = (lane < 20);
    float2 b = {0.f, 0.f};
    if (act) b = ((const float2*)b2)[lane];
    const float vx = ax + b.x, vy = ay + b.y;
    float m = act ? fmaxf(vx, vy) : -INFINITY;
#pragma unroll
    for (int off = 32; off; off >>= 1) m = fmaxf(m, __shfl_xor(m, off, 64));
    float e = act ? (expf(vx - m) + expf(vy - m)) : 0.f;
#pragma unroll
    for (int off = 32; off; off >>= 1) e += __shfl_xor(e, off, 64);
    const float ls = logf(e);
    if (act) {
        float2 o = {vx - m - ls, vy - m - ls};
        ((float2*)out)[n * 20 + lane] = o;
    }
}

extern "C" void kernel_launch(void* const* d_in, const int* in_sizes, int n_in,
                              void* d_out, int out_size, void* d_ws, size_t ws_size,
                              hipStream_t stream) {
    const float* x  = (const float*)d_in[0];
    const int*   ei = (const int*)d_in[1];   // [2, NE]: src then dst
    const float* W1 = (const float*)d_in[2];
    const float* b1 = (const float*)d_in[3];
    const float* W2 = (const float*)d_in[4];
    const float* b2 = (const float*)d_in[5];
    const int* src = ei;
    const int* dst = ei + NE;

    unsigned* H1 = (unsigned*)d_ws;                  // NN*64 uints (bf16x2)
    float*    h  = (float*)(H1 + (size_t)NN * 64);   // NN*128 f32
    unsigned* H2 = (unsigned*)(h + (size_t)NN * 128);// NN*20 uints (bf16x2)
    int* count   = (int*)(H2 + (size_t)NN * 20);     // NN
    int* cursor  = count + NN;                       // NN
    int* rowoff  = cursor + NN;                      // NN+1
    int* eid     = rowoff + NN + 1;                  // NE
    float* out   = (float*)d_out;

    hipMemsetAsync(count, 0, (size_t)NN * 2 * sizeof(int), stream);  // count + cursor

    gemm1_k<<<3125, 256, 0, stream>>>(x, W1, (uint2*)H1, dst, count);
    scan_k<<<1, 1024, 0, stream>>>(count, rowoff);
    fill_k<<<3125, 256, 0, stream>>>(src, dst, rowoff, cursor, eid);
    gather1_k<<<12500, 256, 0, stream>>>(H1, rowoff, eid, b1, (float2*)h);
    gemm2_k<<<7813, 256, 0, stream>>>(h, W2, (unsigned short*)H2);
    gather2_k<<<12500, 256, 0, stream>>>(H2, rowoff, eid, b2, out);
}

// Round 4
// 184.319 us; speedup vs baseline: 1.5577x; 1.5577x over previous
//
#include <hip/hip_runtime.h>

#define NN 50000
#define NE 800000
#define NB 196   // ceil(NN/256)

// ---- bf16 helpers (manual, f32 accumulate everywhere) ----
__device__ __forceinline__ float lof(unsigned v) { return __uint_as_float(v << 16); }
__device__ __forceinline__ float hif(unsigned v) { return __uint_as_float(v & 0xffff0000u); }
__device__ __forceinline__ unsigned bf16rne(float f) {
    unsigned u = __float_as_uint(f);
    return (u + 0x7fffu + ((u >> 16) & 1u)) >> 16;
}
__device__ __forceinline__ unsigned pack2(float a, float b) {
    return bf16rne(a) | (bf16rne(b) << 16);
}

// ---------------- GEMM1 (+fused edge histogram): H1[50000,128](bf16) = x @ W1 ----------------
// 3125 blocks x 256 threads = exactly NE threads -> each also counts one edge.
__global__ __launch_bounds__(256) void gemm1_k(const float* __restrict__ x,
                                               const float* __restrict__ W,
                                               uint2* __restrict__ H1,
                                               const int* __restrict__ dst,
                                               int* __restrict__ count) {
    __shared__ float wl[128 * 128];   // whole W1, 64 KB
    __shared__ float xl[16 * 128];
    const int tid = threadIdx.x;

    // fused histogram: one edge per thread
    atomicAdd(&count[dst[blockIdx.x * 256 + tid]], 1);

    const float4* W4 = (const float4*)W;
    float4* wl4 = (float4*)wl;
#pragma unroll
    for (int i = 0; i < 16; ++i) wl4[tid + 256 * i] = W4[tid + 256 * i];

    const long row0 = (long)blockIdx.x * 16;
    const float4* x4 = (const float4*)(x + row0 * 128);
    float4* xl4 = (float4*)xl;
#pragma unroll
    for (int i = 0; i < 2; ++i) xl4[tid + 256 * i] = x4[tid + 256 * i];
    __syncthreads();

    const int q = tid & 31;    // 4-channel group
    const int rg = tid >> 5;   // rows rg, rg+8
    float4 acc0 = {0.f, 0.f, 0.f, 0.f};
    float4 acc1 = {0.f, 0.f, 0.f, 0.f};
    for (int k = 0; k < 128; ++k) {
        float4 w = wl4[k * 32 + q];
        float a0 = xl[rg * 128 + k];
        float a1 = xl[(rg + 8) * 128 + k];
        acc0.x += a0 * w.x; acc0.y += a0 * w.y; acc0.z += a0 * w.z; acc0.w += a0 * w.w;
        acc1.x += a1 * w.x; acc1.y += a1 * w.y; acc1.z += a1 * w.z; acc1.w += a1 * w.w;
    }
    uint2* out2 = H1 + row0 * 32;
    out2[rg * 32 + q]       = make_uint2(pack2(acc0.x, acc0.y), pack2(acc0.z, acc0.w));
    out2[(rg + 8) * 32 + q] = make_uint2(pack2(acc1.x, acc1.y), pack2(acc1.z, acc1.w));
}

// ---------------- hierarchical scan: count[NN] -> rowoff[NN+1] ----------------
// stage 1: per-256-chunk sums
__global__ __launch_bounds__(256) void reduce_k(const int* __restrict__ count,
                                                int* __restrict__ blocksum) {
    const int idx = blockIdx.x * 256 + threadIdx.x;
    int v = (idx < NN) ? count[idx] : 0;
#pragma unroll
    for (int off = 32; off; off >>= 1) v += __shfl_xor(v, off, 64);
    __shared__ int ws[4];
    if ((threadIdx.x & 63) == 0) ws[threadIdx.x >> 6] = v;
    __syncthreads();
    if (threadIdx.x == 0) blocksum[blockIdx.x] = ws[0] + ws[1] + ws[2] + ws[3];
}

// stage 2: every block re-scans the 196 blocksums locally, then scans its own chunk
__global__ __launch_bounds__(256) void scanfin_k(const int* __restrict__ count,
                                                 const int* __restrict__ blocksum,
                                                 int* __restrict__ rowoff) {
    __shared__ int bs[256];
    __shared__ int sm[256];
    const int t = threadIdx.x;
    bs[t] = (t < NB) ? blocksum[t] : 0;
    __syncthreads();
#pragma unroll
    for (int off = 1; off < 256; off <<= 1) {
        int u = (t >= off) ? bs[t - off] : 0;
        __syncthreads();
        bs[t] += u;
        __syncthreads();
    }
    const int blockoff = (blockIdx.x == 0) ? 0 : bs[blockIdx.x - 1];

    const int idx = blockIdx.x * 256 + t;
    int v = (idx < NN) ? count[idx] : 0;
    sm[t] = v;
    __syncthreads();
#pragma unroll
    for (int off = 1; off < 256; off <<= 1) {
        int u = (t >= off) ? sm[t - off] : 0;
        __syncthreads();
        sm[t] += u;
        __syncthreads();
    }
    if (idx < NN) rowoff[idx] = blockoff + sm[t] - v;   // exclusive
    if (idx == NN) rowoff[NN] = NE;
}

__global__ __launch_bounds__(256) void fill_k(const int* __restrict__ src,
                                              const int* __restrict__ dst,
                                              const int* __restrict__ rowoff,
                                              int* __restrict__ cursor,
                                              int* __restrict__ eid) {
    const int e = blockIdx.x * 256 + threadIdx.x;
    const int d = dst[e];
    const int p = atomicAdd(&cursor[d], 1);
    eid[rowoff[d] + p] = src[e];
}

// ---------------- gather1 + bias + relu: h[n](f32) = relu(sum H1bf16[j] + b1) ----------------
// one wave per node; lane owns 2 channels (one packed uint)
__global__ __launch_bounds__(256) void gather1_k(const unsigned* __restrict__ H1,
                                                 const int* __restrict__ rowoff,
                                                 const int* __restrict__ eid,
                                                 const float* __restrict__ b1,
                                                 float2* __restrict__ h) {
    const int n = blockIdx.x * 4 + (threadIdx.x >> 6);
    const int lane = threadIdx.x & 63;
    const int beg = rowoff[n], end = rowoff[n + 1];
    float ax = 0.f, ay = 0.f;
    int k = beg;
    for (; k + 3 < end; k += 4) {
        const int s0 = eid[k], s1 = eid[k + 1], s2 = eid[k + 2], s3 = eid[k + 3];
        const unsigned v0 = H1[s0 * 64 + lane];
        const unsigned v1 = H1[s1 * 64 + lane];
        const unsigned v2 = H1[s2 * 64 + lane];
        const unsigned v3 = H1[s3 * 64 + lane];
        ax += (lof(v0) + lof(v1)) + (lof(v2) + lof(v3));
        ay += (hif(v0) + hif(v1)) + (hif(v2) + hif(v3));
    }
    for (; k < end; ++k) {
        const unsigned v = H1[eid[k] * 64 + lane];
        ax += lof(v); ay += hif(v);
    }
    const float2 b = ((const float2*)b1)[lane];
    float2 o;
    o.x = fmaxf(ax + b.x, 0.f);
    o.y = fmaxf(ay + b.y, 0.f);
    h[n * 64 + lane] = o;
}

// ---------------- GEMM2: H2[50000,40](bf16) = h(f32) @ W2 ----------------
// one thread per (row, 4-col group): h row re-read 10x (was 40x)
__global__ __launch_bounds__(256) void gemm2_k(const float* __restrict__ h,
                                               const float* __restrict__ W2,
                                               uint2* __restrict__ H2) {
    __shared__ float wl[128 * 40];
    const int tid = threadIdx.x;
    for (int i = tid; i < 128 * 40 / 4; i += 256)
        ((float4*)wl)[i] = ((const float4*)W2)[i];
    __syncthreads();

    const int i = blockIdx.x * 256 + tid;
    if (i >= NN * 10) return;
    const int row = i / 10;
    const int cg = i - row * 10;           // 4 cols: cg*4 .. cg*4+3
    const float4* hrow = (const float4*)(h + (long)row * 128);
    const float4* w4 = (const float4*)(wl + cg * 4);   // stride 10 float4s per k
    float4 acc = {0.f, 0.f, 0.f, 0.f};
#pragma unroll
    for (int k4 = 0; k4 < 32; ++k4) {
        float4 hv = hrow[k4];
        float4 w0 = w4[(k4 * 4 + 0) * 10];
        float4 w1 = w4[(k4 * 4 + 1) * 10];
        float4 w2 = w4[(k4 * 4 + 2) * 10];
        float4 w3 = w4[(k4 * 4 + 3) * 10];
        acc.x += hv.x * w0.x + hv.y * w1.x + hv.z * w2.x + hv.w * w3.x;
        acc.y += hv.x * w0.y + hv.y * w1.y + hv.z * w2.y + hv.w * w3.y;
        acc.z += hv.x * w0.z + hv.y * w1.z + hv.z * w2.z + hv.w * w3.z;
        acc.w += hv.x * w0.w + hv.y * w1.w + hv.z * w2.w + hv.w * w3.w;
    }
    H2[i] = make_uint2(pack2(acc.x, acc.y), pack2(acc.z, acc.w));
}

// ---------------- gather2 + bias + log_softmax ----------------
// one wave per node; 3 edge-groups x 20 lanes, each lane = 2 channels (packed uint)
__global__ __launch_bounds__(256) void gather2_k(const unsigned* __restrict__ H2,
                                                 const int* __restrict__ rowoff,
                                                 const int* __restrict__ eid,
                                                 const float* __restrict__ b2,
                                                 float* __restrict__ out) {
    const int n = blockIdx.x * 4 + (threadIdx.x >> 6);
    const int lane = threadIdx.x & 63;
    const int g = lane / 20;        // edge-group 0..2 (g==3 idle)
    const int c2 = lane - g * 20;   // channel-pair 0..19
    const int beg = rowoff[n], end = rowoff[n + 1];
    float ax = 0.f, ay = 0.f;
    if (g < 3) {
        int k = beg + g;
        for (; k + 3 < end; k += 6) {   // 2 edges per group per iter
            const int s0 = eid[k], s1 = eid[k + 3];
            const unsigned v0 = H2[s0 * 20 + c2];
            const unsigned v1 = H2[s1 * 20 + c2];
            ax += lof(v0) + lof(v1);
            ay += hif(v0) + hif(v1);
        }
        if (k < end) {
            const unsigned v = H2[eid[k] * 20 + c2];
            ax += lof(v); ay += hif(v);
        }
    }
    // combine the 3 groups: lanes 0..19 accumulate lanes +20, +40
    ax += __shfl(ax, lane + 20, 64) + __shfl(ax, lane + 40, 64);
    ay += __shfl(ay, lane + 20, 64) + __shfl(ay, lane + 40, 64);

    const bool act = (lane < 20);
    float2 b = {0.f, 0.f};
    if (act) b = ((const float2*)b2)[lane];
    const float vx = ax + b.x, vy = ay + b.y;
    float m = act ? fmaxf(vx, vy) : -INFINITY;
#pragma unroll
    for (int off = 32; off; off >>= 1) m = fmaxf(m, __shfl_xor(m, off, 64));
    float e = act ? (expf(vx - m) + expf(vy - m)) : 0.f;
#pragma unroll
    for (int off = 32; off; off >>= 1) e += __shfl_xor(e, off, 64);
    const float ls = logf(e);
    if (act) {
        float2 o = {vx - m - ls, vy - m - ls};
        ((float2*)out)[n * 20 + lane] = o;
    }
}

extern "C" void kernel_launch(void* const* d_in, const int* in_sizes, int n_in,
                              void* d_out, int out_size, void* d_ws, size_t ws_size,
                              hipStream_t stream) {
    const float* x  = (const float*)d_in[0];
    const int*   ei = (const int*)d_in[1];   // [2, NE]: src then dst
    const float* W1 = (const float*)d_in[2];
    const float* b1 = (const float*)d_in[3];
    const float* W2 = (const float*)d_in[4];
    const float* b2 = (const float*)d_in[5];
    const int* src = ei;
    const int* dst = ei + NE;

    unsigned* H1 = (unsigned*)d_ws;                   // NN*64 uints (bf16x2)
    float*    h  = (float*)(H1 + (size_t)NN * 64);    // NN*128 f32
    unsigned* H2 = (unsigned*)(h + (size_t)NN * 128); // NN*20 uints (bf16x2)
    int* count    = (int*)(H2 + (size_t)NN * 20);     // NN
    int* cursor   = count + NN;                       // NN
    int* rowoff   = cursor + NN;                      // NN+1
    int* blocksum = rowoff + NN + 1;                  // NB
    int* eid      = blocksum + 256;                   // NE
    float* out    = (float*)d_out;

    hipMemsetAsync(count, 0, (size_t)NN * 2 * sizeof(int), stream);  // count + cursor

    gemm1_k<<<3125, 256, 0, stream>>>(x, W1, (uint2*)H1, dst, count);
    reduce_k<<<NB, 256, 0, stream>>>(count, blocksum);
    scanfin_k<<<NB, 256, 0, stream>>>(count, blocksum, rowoff);
    fill_k<<<3125, 256, 0, stream>>>(src, dst, rowoff, cursor, eid);
    gather1_k<<<12500, 256, 0, stream>>>(H1, rowoff, eid, b1, (float2*)h);
    gemm2_k<<<1954, 256, 0, stream>>>(h, W2, (uint2*)H2);
    gather2_k<<<12500, 256, 0, stream>>>(H2, rowoff, eid, b2, out);
}

// Round 5
// 180.923 us; speedup vs baseline: 1.5869x; 1.0188x over previous
//
#include <hip/hip_runtime.h>

#define NN 50000
#define NE 800000
#define NB 196   // ceil(NN/256)

using short8 = __attribute__((ext_vector_type(8))) short;
using f32x4  = __attribute__((ext_vector_type(4))) float;
union U4S8 { uint4 u; short8 v; };

// ---- bf16 helpers (RNE, f32 accumulate everywhere) ----
__device__ __forceinline__ float lof(unsigned v) { return __uint_as_float(v << 16); }
__device__ __forceinline__ float hif(unsigned v) { return __uint_as_float(v & 0xffff0000u); }
__device__ __forceinline__ unsigned bf16rne(float f) {
    unsigned u = __float_as_uint(f);
    return (u + 0x7fffu + ((u >> 16) & 1u)) >> 16;
}
__device__ __forceinline__ unsigned pack2(float a, float b) {
    return bf16rne(a) | (bf16rne(b) << 16);
}

// ---------------- prep: edge histogram + W1^T/W2^T bf16 pack ----------------
// 3125 x 256 = NE threads; threads 0..8191 also build W1T, 8192..11263 build W2T.
// W1T[n][k] (128x128 bf16, uint-packed k-pairs); W2T[n][k] (48x128, rows 40..47 = 0).
__global__ __launch_bounds__(256) void prep_k(const float* __restrict__ W1,
                                              const float* __restrict__ W2,
                                              const int* __restrict__ dst,
                                              int* __restrict__ count,
                                              unsigned* __restrict__ W1T,
                                              unsigned* __restrict__ W2T) {
    const int t = blockIdx.x * 256 + threadIdx.x;
    atomicAdd(&count[dst[t]], 1);
    if (t < 8192) {
        const int n = t >> 6, k2 = (t & 63) * 2;
        W1T[t] = pack2(W1[k2 * 128 + n], W1[(k2 + 1) * 128 + n]);
    } else if (t < 8192 + 3072) {
        const int u = t - 8192;
        const int n = u >> 6, k2 = (u & 63) * 2;
        W2T[u] = (n < 40) ? pack2(W2[k2 * 40 + n], W2[(k2 + 1) * 40 + n]) : 0u;
    }
}

// ---------------- GEMM1 (MFMA): H1[50000,128](bf16) = bf16(x) @ bf16(W1) ----------------
// 4 waves/block, no LDS. Each wave: whole W1T in 128 VGPRs; loops over 16-row M-tiles.
// mfma_f32_16x16x32_bf16: A row=l&15,k=8*(l>>4)+i ; B col=l&15,k same ; C col=l&15,row=4*(l>>4)+j
__global__ __launch_bounds__(256) void gemm1_k(const float* __restrict__ x,
                                               const unsigned* __restrict__ W1T,
                                               unsigned short* __restrict__ H1) {
    const int lane = threadIdx.x & 63;
    const int cl = lane & 15;
    const int kh = lane >> 4;   // 0..3
    const int gw = (blockIdx.x * 256 + threadIdx.x) >> 6;   // 0..2047

    short8 Bf[8][4];
#pragma unroll
    for (int c = 0; c < 8; ++c)
#pragma unroll
        for (int kc = 0; kc < 4; ++kc) {
            U4S8 tb;
            tb.u = *(const uint4*)(W1T + ((c * 16 + cl) * 128 + kc * 32 + kh * 8) / 2);
            Bf[c][kc] = tb.v;
        }

    for (int mt = gw; mt < 3125; mt += 2048) {   // 50000 = 3125*16, no tail
        const int r0 = mt * 16;
        const float* ap = x + (long)(r0 + cl) * 128 + kh * 8;
        f32x4 acc[8];
#pragma unroll
        for (int c = 0; c < 8; ++c) acc[c] = (f32x4){0.f, 0.f, 0.f, 0.f};
#pragma unroll
        for (int kc = 0; kc < 4; ++kc) {
            const float4 p0 = *(const float4*)(ap + kc * 32);
            const float4 p1 = *(const float4*)(ap + kc * 32 + 4);
            U4S8 af;
            af.u.x = pack2(p0.x, p0.y);
            af.u.y = pack2(p0.z, p0.w);
            af.u.z = pack2(p1.x, p1.y);
            af.u.w = pack2(p1.z, p1.w);
#pragma unroll
            for (int c = 0; c < 8; ++c)
                acc[c] = __builtin_amdgcn_mfma_f32_16x16x32_bf16(af.v, Bf[c][kc], acc[c], 0, 0, 0);
        }
        unsigned short* hp = H1 + (long)(r0 + kh * 4) * 128 + cl;
#pragma unroll
        for (int c = 0; c < 8; ++c)
#pragma unroll
            for (int j = 0; j < 4; ++j)
                hp[j * 128 + c * 16] = (unsigned short)bf16rne(acc[c][j]);
    }
}

// ---------------- hierarchical scan: count[NN] -> rowoff[NN+1] ----------------
__global__ __launch_bounds__(256) void reduce_k(const int* __restrict__ count,
                                                int* __restrict__ blocksum) {
    const int idx = blockIdx.x * 256 + threadIdx.x;
    int v = (idx < NN) ? count[idx] : 0;
#pragma unroll
    for (int off = 32; off; off >>= 1) v += __shfl_xor(v, off, 64);
    __shared__ int ws[4];
    if ((threadIdx.x & 63) == 0) ws[threadIdx.x >> 6] = v;
    __syncthreads();
    if (threadIdx.x == 0) blocksum[blockIdx.x] = ws[0] + ws[1] + ws[2] + ws[3];
}

__global__ __launch_bounds__(256) void scanfin_k(const int* __restrict__ count,
                                                 const int* __restrict__ blocksum,
                                                 int* __restrict__ rowoff) {
    __shared__ int bs[256];
    __shared__ int sm[256];
    const int t = threadIdx.x;
    bs[t] = (t < NB) ? blocksum[t] : 0;
    __syncthreads();
#pragma unroll
    for (int off = 1; off < 256; off <<= 1) {
        int u = (t >= off) ? bs[t - off] : 0;
        __syncthreads();
        bs[t] += u;
        __syncthreads();
    }
    const int blockoff = (blockIdx.x == 0) ? 0 : bs[blockIdx.x - 1];

    const int idx = blockIdx.x * 256 + t;
    int v = (idx < NN) ? count[idx] : 0;
    sm[t] = v;
    __syncthreads();
#pragma unroll
    for (int off = 1; off < 256; off <<= 1) {
        int u = (t >= off) ? sm[t - off] : 0;
        __syncthreads();
        sm[t] += u;
        __syncthreads();
    }
    if (idx < NN) rowoff[idx] = blockoff + sm[t] - v;   // exclusive
    if (idx == NN) rowoff[NN] = NE;
}

__global__ __launch_bounds__(256) void fill_k(const int* __restrict__ src,
                                              const int* __restrict__ dst,
                                              const int* __restrict__ rowoff,
                                              int* __restrict__ cursor,
                                              int* __restrict__ eid) {
    const int e = blockIdx.x * 256 + threadIdx.x;
    const int d = dst[e];
    const int p = atomicAdd(&cursor[d], 1);
    eid[rowoff[d] + p] = src[e];
}

// ---------------- gather1 + bias + relu: h[n](bf16) = relu(sum H1[j] + b1) ----------------
__global__ __launch_bounds__(256) void gather1_k(const unsigned* __restrict__ H1,
                                                 const int* __restrict__ rowoff,
                                                 const int* __restrict__ eid,
                                                 const float* __restrict__ b1,
                                                 unsigned* __restrict__ h) {
    const int n = blockIdx.x * 4 + (threadIdx.x >> 6);
    const int lane = threadIdx.x & 63;
    const int beg = rowoff[n], end = rowoff[n + 1];
    float ax = 0.f, ay = 0.f;
    int k = beg;
    for (; k + 3 < end; k += 4) {
        const int s0 = eid[k], s1 = eid[k + 1], s2 = eid[k + 2], s3 = eid[k + 3];
        const unsigned v0 = H1[s0 * 64 + lane];
        const unsigned v1 = H1[s1 * 64 + lane];
        const unsigned v2 = H1[s2 * 64 + lane];
        const unsigned v3 = H1[s3 * 64 + lane];
        ax += (lof(v0) + lof(v1)) + (lof(v2) + lof(v3));
        ay += (hif(v0) + hif(v1)) + (hif(v2) + hif(v3));
    }
    for (; k < end; ++k) {
        const unsigned v = H1[eid[k] * 64 + lane];
        ax += lof(v); ay += hif(v);
    }
    const float2 b = ((const float2*)b1)[lane];
    h[n * 64 + lane] = pack2(fmaxf(ax + b.x, 0.f), fmaxf(ay + b.y, 0.f));
}

// ---------------- GEMM2 (MFMA): H2[50000,40](bf16) = h(bf16) @ W2 ----------------
__global__ __launch_bounds__(256) void gemm2_k(const unsigned* __restrict__ h,
                                               const unsigned* __restrict__ W2T,
                                               unsigned short* __restrict__ H2) {
    const int lane = threadIdx.x & 63;
    const int cl = lane & 15;
    const int kh = lane >> 4;
    const int gw = (blockIdx.x * 256 + threadIdx.x) >> 6;

    short8 Bf[3][4];
#pragma unroll
    for (int c = 0; c < 3; ++c)
#pragma unroll
        for (int kc = 0; kc < 4; ++kc) {
            U4S8 tb;
            tb.u = *(const uint4*)(W2T + ((c * 16 + cl) * 128 + kc * 32 + kh * 8) / 2);
            Bf[c][kc] = tb.v;
        }

    for (int mt = gw; mt < 3125; mt += 2048) {
        const int r0 = mt * 16;
        const unsigned* ap = h + (long)(r0 + cl) * 64 + kh * 4;
        f32x4 acc[3];
#pragma unroll
        for (int c = 0; c < 3; ++c) acc[c] = (f32x4){0.f, 0.f, 0.f, 0.f};
#pragma unroll
        for (int kc = 0; kc < 4; ++kc) {
            U4S8 af;
            af.u = *(const uint4*)(ap + kc * 16);
#pragma unroll
            for (int c = 0; c < 3; ++c)
                acc[c] = __builtin_amdgcn_mfma_f32_16x16x32_bf16(af.v, Bf[c][kc], acc[c], 0, 0, 0);
        }
        unsigned short* hp = H2 + (long)(r0 + kh * 4) * 40;
#pragma unroll
        for (int c = 0; c < 3; ++c) {
            const int col = c * 16 + cl;
            if (col < 40) {
#pragma unroll
                for (int j = 0; j < 4; ++j)
                    hp[j * 40 + col] = (unsigned short)bf16rne(acc[c][j]);
            }
        }
    }
}

// ---------------- gather2 + bias + log_softmax ----------------
__global__ __launch_bounds__(256) void gather2_k(const unsigned* __restrict__ H2,
                                                 const int* __restrict__ rowoff,
                                                 const int* __restrict__ eid,
                                                 const float* __restrict__ b2,
                                                 float* __restrict__ out) {
    const int n = blockIdx.x * 4 + (threadIdx.x >> 6);
    const int lane = threadIdx.x & 63;
    const int g = lane / 20;        // edge-group 0..2 (g==3 idle)
    const int c2 = lane - g * 20;   // channel-pair 0..19
    const int beg = rowoff[n], end = rowoff[n + 1];
    float ax = 0.f, ay = 0.f;
    if (g < 3) {
        int k = beg + g;
        for (; k + 3 < end; k += 6) {
            const int s0 = eid[k], s1 = eid[k + 3];
            const unsigned v0 = H2[s0 * 20 + c2];
            const unsigned v1 = H2[s1 * 20 + c2];
            ax += lof(v0) + lof(v1);
            ay += hif(v0) + hif(v1);
        }
        if (k < end) {
            const unsigned v = H2[eid[k] * 20 + c2];
            ax += lof(v); ay += hif(v);
        }
    }
    ax += __shfl(ax, lane + 20, 64) + __shfl(ax, lane + 40, 64);
    ay += __shfl(ay, lane + 20, 64) + __shfl(ay, lane + 40, 64);

    const bool act = (lane < 20);
    float2 b = {0.f, 0.f};
    if (act) b = ((const float2*)b2)[lane];
    const float vx = ax + b.x, vy = ay + b.y;
    float m = act ? fmaxf(vx, vy) : -INFINITY;
#pragma unroll
    for (int off = 32; off; off >>= 1) m = fmaxf(m, __shfl_xor(m, off, 64));
    float e = act ? (expf(vx - m) + expf(vy - m)) : 0.f;
#pragma unroll
    for (int off = 32; off; off >>= 1) e += __shfl_xor(e, off, 64);
    const float ls = logf(e);
    if (act) {
        float2 o = {vx - m - ls, vy - m - ls};
        ((float2*)out)[n * 20 + lane] = o;
    }
}

extern "C" void kernel_launch(void* const* d_in, const int* in_sizes, int n_in,
                              void* d_out, int out_size, void* d_ws, size_t ws_size,
                              hipStream_t stream) {
    const float* x  = (const float*)d_in[0];
    const int*   ei = (const int*)d_in[1];   // [2, NE]: src then dst
    const float* W1 = (const float*)d_in[2];
    const float* b1 = (const float*)d_in[3];
    const float* W2 = (const float*)d_in[4];
    const float* b2 = (const float*)d_in[5];
    const int* src = ei;
    const int* dst = ei + NE;

    unsigned* H1  = (unsigned*)d_ws;                  // NN*64 (bf16x2)
    unsigned* h   = H1 + (size_t)NN * 64;             // NN*64 (bf16x2)
    unsigned* H2  = h + (size_t)NN * 64;              // NN*20 (bf16x2)
    unsigned* W1T = H2 + (size_t)NN * 20;             // 8192
    unsigned* W2T = W1T + 8192;                       // 3072
    int* count    = (int*)(W2T + 3072);               // NN
    int* cursor   = count + NN;                       // NN
    int* rowoff   = cursor + NN;                      // NN+1
    int* blocksum = rowoff + NN + 1;                  // NB
    int* eid      = blocksum + 256;                   // NE
    float* out    = (float*)d_out;

    hipMemsetAsync(count, 0, (size_t)NN * 2 * sizeof(int), stream);  // count + cursor

    prep_k<<<3125, 256, 0, stream>>>(W1, W2, dst, count, W1T, W2T);
    reduce_k<<<NB, 256, 0, stream>>>(count, blocksum);
    scanfin_k<<<NB, 256, 0, stream>>>(count, blocksum, rowoff);
    fill_k<<<3125, 256, 0, stream>>>(src, dst, rowoff, cursor, eid);
    gemm1_k<<<512, 256, 0, stream>>>(x, W1T, (unsigned short*)H1);
    gather1_k<<<12500, 256, 0, stream>>>(H1, rowoff, eid, b1, h);
    gemm2_k<<<512, 256, 0, stream>>>(h, W2T, (unsigned short*)H2);
    gather2_k<<<12500, 256, 0, stream>>>(H2, rowoff, eid, b2, out);
}

// Round 6
// 138.376 us; speedup vs baseline: 2.0748x; 1.3075x over previous
//
#include <hip/hip_runtime.h>

#define NN 50000
#define NE 800000
#define NBKT 196      // dst>>8 buckets: 196*256 = 50176 >= NN
#define NB_BIN 128    // blocks in binning kernels
#define EPB (NE / NB_BIN)          // 6250 edges per bin block
#define MATN (NBKT * NB_BIN)       // 25088
#define CH 25                      // ceil(MATN/1024)

using short8 = __attribute__((ext_vector_type(8))) short;
using f32x4  = __attribute__((ext_vector_type(4))) float;
union U4S8 { uint4 u; short8 v; };

// ---- bf16 helpers (RNE, f32 accumulate everywhere) ----
__device__ __forceinline__ float lof(unsigned v) { return __uint_as_float(v << 16); }
__device__ __forceinline__ float hif(unsigned v) { return __uint_as_float(v & 0xffff0000u); }
__device__ __forceinline__ unsigned bf16rne(float f) {
    unsigned u = __float_as_uint(f);
    return (u + 0x7fffu + ((u >> 16) & 1u)) >> 16;
}
__device__ __forceinline__ unsigned pack2(float a, float b) {
    return bf16rne(a) | (bf16rne(b) << 16);
}

// ---------------- K1: per-block bucket histogram (+ weight bf16 pack) ----------------
__global__ __launch_bounds__(256) void binhist_k(const int* __restrict__ dst,
                                                 int* __restrict__ mat,
                                                 const float* __restrict__ W1,
                                                 const float* __restrict__ W2,
                                                 unsigned* __restrict__ W1T,
                                                 unsigned* __restrict__ W2T) {
    __shared__ int hist[NBKT];
    const int tid = threadIdx.x;
    for (int i = tid; i < NBKT; i += 256) hist[i] = 0;

    const int g = blockIdx.x * 256 + tid;
    if (g < 8192) {
        const int n = g >> 6, k2 = (g & 63) * 2;
        W1T[g] = pack2(W1[k2 * 128 + n], W1[(k2 + 1) * 128 + n]);
    } else if (g < 8192 + 3072) {
        const int u = g - 8192;
        const int n = u >> 6, k2 = (u & 63) * 2;
        W2T[u] = (n < 40) ? pack2(W2[k2 * 40 + n], W2[(k2 + 1) * 40 + n]) : 0u;
    }
    __syncthreads();

    const int base = blockIdx.x * EPB;
    for (int e = base + tid; e < base + EPB; e += 256)
        atomicAdd(&hist[dst[e] >> 8], 1);
    __syncthreads();
    for (int i = tid; i < NBKT; i += 256)
        mat[i * NB_BIN + blockIdx.x] = hist[i];
}

// ---------------- K2: exclusive scan of mat[MATN] in place (single block) ----------------
__global__ __launch_bounds__(1024) void matscan_k(int* __restrict__ mat) {
    __shared__ int lds[MATN];
    __shared__ int tsum[1024];
    const int t = threadIdx.x;
    for (int i = t; i < MATN; i += 1024) lds[i] = mat[i];
    __syncthreads();
    int s = 0;
    const int b0 = t * CH;
#pragma unroll
    for (int i = 0; i < CH; ++i) {
        const int idx = b0 + i;
        if (idx < MATN) s += lds[idx];
    }
    tsum[t] = s;
    __syncthreads();
#pragma unroll
    for (int off = 1; off < 1024; off <<= 1) {
        int u = (t >= off) ? tsum[t - off] : 0;
        __syncthreads();
        tsum[t] += u;
        __syncthreads();
    }
    int run = tsum[t] - s;   // exclusive prefix of this thread's chunk
#pragma unroll
    for (int i = 0; i < CH; ++i) {
        const int idx = b0 + i;
        if (idx < MATN) { const int v = lds[idx]; lds[idx] = run; run += v; }
    }
    __syncthreads();
    for (int i = t; i < MATN; i += 1024) mat[i] = lds[i];
}

// ---------------- K3: scatter (dst,src) into bucket-ordered binned[] ----------------
__global__ __launch_bounds__(256) void binscatter_k(const int* __restrict__ src,
                                                    const int* __restrict__ dst,
                                                    const int* __restrict__ mat,
                                                    uint2* __restrict__ binned) {
    __shared__ int cur[NBKT];
    const int tid = threadIdx.x;
    for (int i = tid; i < NBKT; i += 256) cur[i] = mat[i * NB_BIN + blockIdx.x];
    __syncthreads();
    const int base = blockIdx.x * EPB;
    for (int e = base + tid; e < base + EPB; e += 256) {
        const int d = dst[e];
        const int p = atomicAdd(&cur[d >> 8], 1);
        binned[p] = make_uint2((unsigned)d, (unsigned)src[e]);
    }
}

// ---------------- K4: per-bucket CSR (rowoff + eid), all node work in LDS ----------------
__global__ __launch_bounds__(256) void bucketcsr_k(const uint2* __restrict__ binned,
                                                   const int* __restrict__ mat,
                                                   int* __restrict__ rowoff,
                                                   int* __restrict__ eid) {
    __shared__ int cnt[256];
    __shared__ int off[256];
    const int b = blockIdx.x;
    const int tid = threadIdx.x;
    const int beg = mat[b * NB_BIN];
    const int end = (b == NBKT - 1) ? NE : mat[(b + 1) * NB_BIN];
    cnt[tid] = 0;
    __syncthreads();
    for (int i = beg + tid; i < end; i += 256)
        atomicAdd(&cnt[binned[i].x & 255u], 1);
    __syncthreads();
    const int v = cnt[tid];
    off[tid] = v;
    __syncthreads();
#pragma unroll
    for (int o = 1; o < 256; o <<= 1) {
        int u = (tid >= o) ? off[tid - o] : 0;
        __syncthreads();
        off[tid] += u;
        __syncthreads();
    }
    const int excl = off[tid] - v;
    const int node = b * 256 + tid;
    if (node <= NN) rowoff[node] = beg + excl;
    cnt[tid] = excl;   // cursor
    __syncthreads();
    for (int i = beg + tid; i < end; i += 256) {
        const uint2 e = binned[i];
        const int p = atomicAdd(&cnt[e.x & 255u], 1);
        eid[beg + p] = (int)e.y;
    }
}

// ---------------- GEMM1 (MFMA): H1[50000,128](bf16) = bf16(x) @ bf16(W1) ----------------
__global__ __launch_bounds__(256) void gemm1_k(const float* __restrict__ x,
                                               const unsigned* __restrict__ W1T,
                                               unsigned short* __restrict__ H1) {
    const int lane = threadIdx.x & 63;
    const int cl = lane & 15;
    const int kh = lane >> 4;   // 0..3
    const int gw = (blockIdx.x * 256 + threadIdx.x) >> 6;   // 0..2047

    short8 Bf[8][4];
#pragma unroll
    for (int c = 0; c < 8; ++c)
#pragma unroll
        for (int kc = 0; kc < 4; ++kc) {
            U4S8 tb;
            tb.u = *(const uint4*)(W1T + ((c * 16 + cl) * 128 + kc * 32 + kh * 8) / 2);
            Bf[c][kc] = tb.v;
        }

    for (int mt = gw; mt < 3125; mt += 2048) {
        const int r0 = mt * 16;
        const float* ap = x + (long)(r0 + cl) * 128 + kh * 8;
        f32x4 acc[8];
#pragma unroll
        for (int c = 0; c < 8; ++c) acc[c] = (f32x4){0.f, 0.f, 0.f, 0.f};
#pragma unroll
        for (int kc = 0; kc < 4; ++kc) {
            const float4 p0 = *(const float4*)(ap + kc * 32);
            const float4 p1 = *(const float4*)(ap + kc * 32 + 4);
            U4S8 af;
            af.u.x = pack2(p0.x, p0.y);
            af.u.y = pack2(p0.z, p0.w);
            af.u.z = pack2(p1.x, p1.y);
            af.u.w = pack2(p1.z, p1.w);
#pragma unroll
            for (int c = 0; c < 8; ++c)
                acc[c] = __builtin_amdgcn_mfma_f32_16x16x32_bf16(af.v, Bf[c][kc], acc[c], 0, 0, 0);
        }
        unsigned short* hp = H1 + (long)(r0 + kh * 4) * 128 + cl;
#pragma unroll
        for (int c = 0; c < 8; ++c)
#pragma unroll
            for (int j = 0; j < 4; ++j)
                hp[j * 128 + c * 16] = (unsigned short)bf16rne(acc[c][j]);
    }
}

// ---------------- gather1 + bias + relu: h[n](bf16) = relu(sum H1[j] + b1) ----------------
__global__ __launch_bounds__(256) void gather1_k(const unsigned* __restrict__ H1,
                                                 const int* __restrict__ rowoff,
                                                 const int* __restrict__ eid,
                                                 const float* __restrict__ b1,
                                                 unsigned* __restrict__ h) {
    const int n = blockIdx.x * 4 + (threadIdx.x >> 6);
    const int lane = threadIdx.x & 63;
    const int beg = rowoff[n], end = rowoff[n + 1];
    float ax = 0.f, ay = 0.f;
    int k = beg;
    for (; k + 3 < end; k += 4) {
        const int s0 = eid[k], s1 = eid[k + 1], s2 = eid[k + 2], s3 = eid[k + 3];
        const unsigned v0 = H1[s0 * 64 + lane];
        const unsigned v1 = H1[s1 * 64 + lane];
        const unsigned v2 = H1[s2 * 64 + lane];
        const unsigned v3 = H1[s3 * 64 + lane];
        ax += (lof(v0) + lof(v1)) + (lof(v2) + lof(v3));
        ay += (hif(v0) + hif(v1)) + (hif(v2) + hif(v3));
    }
    for (; k < end; ++k) {
        const unsigned v = H1[eid[k] * 64 + lane];
        ax += lof(v); ay += hif(v);
    }
    const float2 b = ((const float2*)b1)[lane];
    h[n * 64 + lane] = pack2(fmaxf(ax + b.x, 0.f), fmaxf(ay + b.y, 0.f));
}

// ---------------- GEMM2 (MFMA): H2[50000,40](bf16) = h(bf16) @ W2 ----------------
__global__ __launch_bounds__(256) void gemm2_k(const unsigned* __restrict__ h,
                                               const unsigned* __restrict__ W2T,
                                               unsigned short* __restrict__ H2) {
    const int lane = threadIdx.x & 63;
    const int cl = lane & 15;
    const int kh = lane >> 4;
    const int gw = (blockIdx.x * 256 + threadIdx.x) >> 6;

    short8 Bf[3][4];
#pragma unroll
    for (int c = 0; c < 3; ++c)
#pragma unroll
        for (int kc = 0; kc < 4; ++kc) {
            U4S8 tb;
            tb.u = *(const uint4*)(W2T + ((c * 16 + cl) * 128 + kc * 32 + kh * 8) / 2);
            Bf[c][kc] = tb.v;
        }

    for (int mt = gw; mt < 3125; mt += 2048) {
        const int r0 = mt * 16;
        const unsigned* ap = h + (long)(r0 + cl) * 64 + kh * 4;
        f32x4 acc[3];
#pragma unroll
        for (int c = 0; c < 3; ++c) acc[c] = (f32x4){0.f, 0.f, 0.f, 0.f};
#pragma unroll
        for (int kc = 0; kc < 4; ++kc) {
            U4S8 af;
            af.u = *(const uint4*)(ap + kc * 16);
#pragma unroll
            for (int c = 0; c < 3; ++c)
                acc[c] = __builtin_amdgcn_mfma_f32_16x16x32_bf16(af.v, Bf[c][kc], acc[c], 0, 0, 0);
        }
        unsigned short* hp = H2 + (long)(r0 + kh * 4) * 40;
#pragma unroll
        for (int c = 0; c < 3; ++c) {
            const int col = c * 16 + cl;
            if (col < 40) {
#pragma unroll
                for (int j = 0; j < 4; ++j)
                    hp[j * 40 + col] = (unsigned short)bf16rne(acc[c][j]);
            }
        }
    }
}

// ---------------- gather2 + bias + log_softmax ----------------
__global__ __launch_bounds__(256) void gather2_k(const unsigned* __restrict__ H2,
                                                 const int* __restrict__ rowoff,
                                                 const int* __restrict__ eid,
                                                 const float* __restrict__ b2,
                                                 float* __restrict__ out) {
    const int n = blockIdx.x * 4 + (threadIdx.x >> 6);
    const int lane = threadIdx.x & 63;
    const int g = lane / 20;        // edge-group 0..2 (g==3 idle)
    const int c2 = lane - g * 20;   // channel-pair 0..19
    const int beg = rowoff[n], end = rowoff[n + 1];
    float ax = 0.f, ay = 0.f;
    if (g < 3) {
        int k = beg + g;
        for (; k + 3 < end; k += 6) {
            const int s0 = eid[k], s1 = eid[k + 3];
            const unsigned v0 = H2[s0 * 20 + c2];
            const unsigned v1 = H2[s1 * 20 + c2];
            ax += lof(v0) + lof(v1);
            ay += hif(v0) + hif(v1);
        }
        if (k < end) {
            const unsigned v = H2[eid[k] * 20 + c2];
            ax += lof(v); ay += hif(v);
        }
    }
    ax += __shfl(ax, lane + 20, 64) + __shfl(ax, lane + 40, 64);
    ay += __shfl(ay, lane + 20, 64) + __shfl(ay, lane + 40, 64);

    const bool act = (lane < 20);
    float2 b = {0.f, 0.f};
    if (act) b = ((const float2*)b2)[lane];
    const float vx = ax + b.x, vy = ay + b.y;
    float m = act ? fmaxf(vx, vy) : -INFINITY;
#pragma unroll
    for (int off = 32; off; off >>= 1) m = fmaxf(m, __shfl_xor(m, off, 64));
    float e = act ? (expf(vx - m) + expf(vy - m)) : 0.f;
#pragma unroll
    for (int off = 32; off; off >>= 1) e += __shfl_xor(e, off, 64);
    const float ls = logf(e);
    if (act) {
        float2 o = {vx - m - ls, vy - m - ls};
        ((float2*)out)[n * 20 + lane] = o;
    }
}

extern "C" void kernel_launch(void* const* d_in, const int* in_sizes, int n_in,
                              void* d_out, int out_size, void* d_ws, size_t ws_size,
                              hipStream_t stream) {
    const float* x  = (const float*)d_in[0];
    const int*   ei = (const int*)d_in[1];   // [2, NE]: src then dst
    const float* W1 = (const float*)d_in[2];
    const float* b1 = (const float*)d_in[3];
    const float* W2 = (const float*)d_in[4];
    const float* b2 = (const float*)d_in[5];
    const int* src = ei;
    const int* dst = ei + NE;

    unsigned* H1  = (unsigned*)d_ws;                  // NN*64 (bf16x2)
    unsigned* h   = H1 + (size_t)NN * 64;             // NN*64 (bf16x2); binned aliases this
    unsigned* H2  = h + (size_t)NN * 64;              // NN*20 (bf16x2)
    unsigned* W1T = H2 + (size_t)NN * 20;             // 8192
    unsigned* W2T = W1T + 8192;                       // 3072
    int* mat      = (int*)(W2T + 3072);               // MATN
    int* rowoff   = mat + MATN;                       // NN+1
    int* eid      = rowoff + NN + 1;                  // NE
    uint2* binned = (uint2*)h;                        // NE uint2 (6.4MB <= 12.8MB of h)
    float* out    = (float*)d_out;

    binhist_k<<<NB_BIN, 256, 0, stream>>>(dst, mat, W1, W2, W1T, W2T);
    matscan_k<<<1, 1024, 0, stream>>>(mat);
    binscatter_k<<<NB_BIN, 256, 0, stream>>>(src, dst, mat, binned);
    bucketcsr_k<<<NBKT, 256, 0, stream>>>(binned, mat, rowoff, eid);
    gemm1_k<<<512, 256, 0, stream>>>(x, W1T, (unsigned short*)H1);
    gather1_k<<<12500, 256, 0, stream>>>(H1, rowoff, eid, b1, h);
    gemm2_k<<<512, 256, 0, stream>>>(h, W2T, (unsigned short*)H2);
    gather2_k<<<12500, 256, 0, stream>>>(H2, rowoff, eid, b2, out);
}

// Round 7
// 129.619 us; speedup vs baseline: 2.2150x; 1.0676x over previous
//
#include <hip/hip_runtime.h>

#define NN 50000
#define NE 800000
#define NBKT 196      // dst>>8 buckets: 196*256 = 50176 >= NN
#define NB_BIN 128    // blocks in binning kernels
#define EPB (NE / NB_BIN)          // 6250 edges per bin block
#define MATN (NBKT * NB_BIN)       // 25088 = 256*98

using short8 = __attribute__((ext_vector_type(8))) short;
using f32x4  = __attribute__((ext_vector_type(4))) float;
union U4S8 { uint4 u; short8 v; };

// ---- bf16 helpers (RNE, f32 accumulate everywhere) ----
__device__ __forceinline__ float lof(unsigned v) { return __uint_as_float(v << 16); }
__device__ __forceinline__ float hif(unsigned v) { return __uint_as_float(v & 0xffff0000u); }
__device__ __forceinline__ unsigned bf16rne(float f) {
    unsigned u = __float_as_uint(f);
    return (u + 0x7fffu + ((u >> 16) & 1u)) >> 16;
}
__device__ __forceinline__ unsigned pack2(float a, float b) {
    return bf16rne(a) | (bf16rne(b) << 16);
}

// ---------------- K1: per-block bucket histogram (+ weight bf16 pack) ----------------
__global__ __launch_bounds__(256) void binhist_k(const int* __restrict__ dst,
                                                 int* __restrict__ mat,
                                                 const float* __restrict__ W1,
                                                 const float* __restrict__ W2,
                                                 unsigned* __restrict__ W1T,
                                                 unsigned* __restrict__ W2T) {
    __shared__ int hist[NBKT];
    const int tid = threadIdx.x;
    for (int i = tid; i < NBKT; i += 256) hist[i] = 0;

    const int g = blockIdx.x * 256 + tid;
    if (g < 8192) {
        const int n = g >> 6, k2 = (g & 63) * 2;
        W1T[g] = pack2(W1[k2 * 128 + n], W1[(k2 + 1) * 128 + n]);
    } else if (g < 8192 + 3072) {
        const int u = g - 8192;
        const int n = u >> 6, k2 = (u & 63) * 2;
        W2T[u] = (n < 40) ? pack2(W2[k2 * 40 + n], W2[(k2 + 1) * 40 + n]) : 0u;
    }
    __syncthreads();

    const int base = blockIdx.x * EPB;
    for (int e = base + tid; e < base + EPB; e += 256)
        atomicAdd(&hist[dst[e] >> 8], 1);
    __syncthreads();
    for (int i = tid; i < NBKT; i += 256)
        mat[i * NB_BIN + blockIdx.x] = hist[i];
}

// ---------------- K2: scatter into bucket order; each block scans mat in LDS ----------------
// (scan replicated per block -> no single-block scan kernel; scanned LDS = cursors)
__global__ __launch_bounds__(256) void binscatter_k(const int* __restrict__ src,
                                                    const int* __restrict__ dst,
                                                    const int* __restrict__ mat,
                                                    uint2* __restrict__ binned,
                                                    int* __restrict__ bucketoff) {
    __shared__ int lds[MATN];   // 100 KB
    __shared__ int tsum[256];
    const int tid = threadIdx.x;
    for (int i = tid; i < MATN; i += 256) lds[i] = mat[i];
    __syncthreads();
    const int b0 = tid * (MATN / 256);   // 98 each, exact
    int s = 0;
#pragma unroll 7
    for (int i = 0; i < MATN / 256; ++i) s += lds[b0 + i];
    tsum[tid] = s;
    __syncthreads();
#pragma unroll
    for (int off = 1; off < 256; off <<= 1) {
        int u = (tid >= off) ? tsum[tid - off] : 0;
        __syncthreads();
        tsum[tid] += u;
        __syncthreads();
    }
    int run = tsum[tid] - s;   // exclusive prefix of this thread's chunk
#pragma unroll 7
    for (int i = 0; i < MATN / 256; ++i) {
        const int v = lds[b0 + i]; lds[b0 + i] = run; run += v;
    }
    __syncthreads();

    if (blockIdx.x == 0) {   // uniform branch: emit bucket boundaries
        for (int i = tid; i < NBKT; i += 256) bucketoff[i] = lds[i * NB_BIN];
        if (tid == 0) bucketoff[NBKT] = NE;
        __syncthreads();     // boundaries out before cursors mutate
    }

    const int base = blockIdx.x * EPB;
    for (int e = base + tid; e < base + EPB; e += 256) {
        const int d = dst[e];
        const int p = atomicAdd(&lds[(d >> 8) * NB_BIN + blockIdx.x], 1);
        binned[p] = make_uint2((unsigned)d, (unsigned)src[e]);
    }
}

// ---------------- K3: per-bucket CSR (rowoff + eid), all node work in LDS ----------------
__global__ __launch_bounds__(256) void bucketcsr_k(const uint2* __restrict__ binned,
                                                   const int* __restrict__ bucketoff,
                                                   int* __restrict__ rowoff,
                                                   int* __restrict__ eid) {
    __shared__ int cnt[256];
    __shared__ int off[256];
    const int b = blockIdx.x;
    const int tid = threadIdx.x;
    const int beg = bucketoff[b];
    const int end = bucketoff[b + 1];
    cnt[tid] = 0;
    __syncthreads();
    for (int i = beg + tid; i < end; i += 256)
        atomicAdd(&cnt[binned[i].x & 255u], 1);
    __syncthreads();
    const int v = cnt[tid];
    off[tid] = v;
    __syncthreads();
#pragma unroll
    for (int o = 1; o < 256; o <<= 1) {
        int u = (tid >= o) ? off[tid - o] : 0;
        __syncthreads();
        off[tid] += u;
        __syncthreads();
    }
    const int excl = off[tid] - v;
    const int node = b * 256 + tid;
    if (node <= NN) rowoff[node] = beg + excl;
    cnt[tid] = excl;   // cursor
    __syncthreads();
    for (int i = beg + tid; i < end; i += 256) {
        const uint2 e = binned[i];
        const int p = atomicAdd(&cnt[e.x & 255u], 1);
        eid[beg + p] = (int)e.y;
    }
}

// ---------------- GEMM1 (MFMA): H1[50000,128](bf16) = bf16(x) @ bf16(W1) ----------------
__global__ __launch_bounds__(256) void gemm1_k(const float* __restrict__ x,
                                               const unsigned* __restrict__ W1T,
                                               unsigned short* __restrict__ H1) {
    const int lane = threadIdx.x & 63;
    const int cl = lane & 15;
    const int kh = lane >> 4;   // 0..3
    const int gw = (blockIdx.x * 256 + threadIdx.x) >> 6;   // 0..2047

    short8 Bf[8][4];
#pragma unroll
    for (int c = 0; c < 8; ++c)
#pragma unroll
        for (int kc = 0; kc < 4; ++kc) {
            U4S8 tb;
            tb.u = *(const uint4*)(W1T + ((c * 16 + cl) * 128 + kc * 32 + kh * 8) / 2);
            Bf[c][kc] = tb.v;
        }

    for (int mt = gw; mt < 3125; mt += 2048) {
        const int r0 = mt * 16;
        const float* ap = x + (long)(r0 + cl) * 128 + kh * 8;
        f32x4 acc[8];
#pragma unroll
        for (int c = 0; c < 8; ++c) acc[c] = (f32x4){0.f, 0.f, 0.f, 0.f};
#pragma unroll
        for (int kc = 0; kc < 4; ++kc) {
            const float4 p0 = *(const float4*)(ap + kc * 32);
            const float4 p1 = *(const float4*)(ap + kc * 32 + 4);
            U4S8 af;
            af.u.x = pack2(p0.x, p0.y);
            af.u.y = pack2(p0.z, p0.w);
            af.u.z = pack2(p1.x, p1.y);
            af.u.w = pack2(p1.z, p1.w);
#pragma unroll
            for (int c = 0; c < 8; ++c)
                acc[c] = __builtin_amdgcn_mfma_f32_16x16x32_bf16(af.v, Bf[c][kc], acc[c], 0, 0, 0);
        }
        unsigned short* hp = H1 + (long)(r0 + kh * 4) * 128 + cl;
#pragma unroll
        for (int c = 0; c < 8; ++c)
#pragma unroll
            for (int j = 0; j < 4; ++j)
                hp[j * 128 + c * 16] = (unsigned short)bf16rne(acc[c][j]);
    }
}

// ---------------- gather1 + bias + relu: h[n](bf16) = relu(sum H1[j] + b1) ----------------
// one wave per node: 2 edge-slots x 32 lanes x uint2 (4 ch per lane)
__global__ __launch_bounds__(256) void gather1_k(const uint2* __restrict__ H1,
                                                 const int* __restrict__ rowoff,
                                                 const int* __restrict__ eid,
                                                 const float* __restrict__ b1,
                                                 uint2* __restrict__ h) {
    const int n = blockIdx.x * 4 + (threadIdx.x >> 6);
    const int lane = threadIdx.x & 63;
    const int half = lane >> 5;       // edge slot 0/1
    const int c4 = lane & 31;         // 4-channel group
    const int beg = rowoff[n], end = rowoff[n + 1];
    float ax = 0.f, ay = 0.f, az = 0.f, aw = 0.f;
    int k = beg;
    for (; k + 7 < end; k += 8) {
        const int sA = eid[k + half];
        const int sB = eid[k + 2 + half];
        const int sC = eid[k + 4 + half];
        const int sD = eid[k + 6 + half];
        const uint2 vA = H1[sA * 32 + c4];
        const uint2 vB = H1[sB * 32 + c4];
        const uint2 vC = H1[sC * 32 + c4];
        const uint2 vD = H1[sD * 32 + c4];
        ax += (lof(vA.x) + lof(vB.x)) + (lof(vC.x) + lof(vD.x));
        ay += (hif(vA.x) + hif(vB.x)) + (hif(vC.x) + hif(vD.x));
        az += (lof(vA.y) + lof(vB.y)) + (lof(vC.y) + lof(vD.y));
        aw += (hif(vA.y) + hif(vB.y)) + (hif(vC.y) + hif(vD.y));
    }
    for (; k + half < end; k += 2) {
        const uint2 v = H1[eid[k + half] * 32 + c4];
        ax += lof(v.x); ay += hif(v.x);
        az += lof(v.y); aw += hif(v.y);
    }
    ax += __shfl_xor(ax, 32, 64);
    ay += __shfl_xor(ay, 32, 64);
    az += __shfl_xor(az, 32, 64);
    aw += __shfl_xor(aw, 32, 64);
    if (half == 0) {
        const float4 b = ((const float4*)b1)[c4];
        uint2 o;
        o.x = pack2(fmaxf(ax + b.x, 0.f), fmaxf(ay + b.y, 0.f));
        o.y = pack2(fmaxf(az + b.z, 0.f), fmaxf(aw + b.w, 0.f));
        h[n * 32 + c4] = o;
    }
}

// ---------------- GEMM2 (MFMA): H2[50000, pad 64](bf16) = h(bf16) @ W2 ----------------
// row stride 64 shorts = 128 B -> each gather2 row read is exactly one cache line
__global__ __launch_bounds__(256) void gemm2_k(const unsigned* __restrict__ h,
                                               const unsigned* __restrict__ W2T,
                                               unsigned short* __restrict__ H2) {
    const int lane = threadIdx.x & 63;
    const int cl = lane & 15;
    const int kh = lane >> 4;
    const int gw = (blockIdx.x * 256 + threadIdx.x) >> 6;

    short8 Bf[3][4];
#pragma unroll
    for (int c = 0; c < 3; ++c)
#pragma unroll
        for (int kc = 0; kc < 4; ++kc) {
            U4S8 tb;
            tb.u = *(const uint4*)(W2T + ((c * 16 + cl) * 128 + kc * 32 + kh * 8) / 2);
            Bf[c][kc] = tb.v;
        }

    for (int mt = gw; mt < 3125; mt += 2048) {
        const int r0 = mt * 16;
        const unsigned* ap = h + (long)(r0 + cl) * 64 + kh * 4;
        f32x4 acc[3];
#pragma unroll
        for (int c = 0; c < 3; ++c) acc[c] = (f32x4){0.f, 0.f, 0.f, 0.f};
#pragma unroll
        for (int kc = 0; kc < 4; ++kc) {
            U4S8 af;
            af.u = *(const uint4*)(ap + kc * 16);
#pragma unroll
            for (int c = 0; c < 3; ++c)
                acc[c] = __builtin_amdgcn_mfma_f32_16x16x32_bf16(af.v, Bf[c][kc], acc[c], 0, 0, 0);
        }
        unsigned short* hp = H2 + (long)(r0 + kh * 4) * 64;
#pragma unroll
        for (int c = 0; c < 3; ++c) {
            const int col = c * 16 + cl;
            if (col < 40) {
#pragma unroll
                for (int j = 0; j < 4; ++j)
                    hp[j * 64 + col] = (unsigned short)bf16rne(acc[c][j]);
            }
        }
    }
}

// ---------------- gather2 + bias + log_softmax (H2 row stride 32 uints) ----------------
__global__ __launch_bounds__(256) void gather2_k(const unsigned* __restrict__ H2,
                                                 const int* __restrict__ rowoff,
                                                 const int* __restrict__ eid,
                                                 const float* __restrict__ b2,
                                                 float* __restrict__ out) {
    const int n = blockIdx.x * 4 + (threadIdx.x >> 6);
    const int lane = threadIdx.x & 63;
    const int g = lane / 20;        // edge-group 0..2 (g==3 idle)
    const int c2 = lane - g * 20;   // channel-pair 0..19
    const int beg = rowoff[n], end = rowoff[n + 1];
    float ax = 0.f, ay = 0.f;
    if (g < 3) {
        int k = beg + g;
        for (; k + 3 < end; k += 6) {
            const int s0 = eid[k], s1 = eid[k + 3];
            const unsigned v0 = H2[s0 * 32 + c2];
            const unsigned v1 = H2[s1 * 32 + c2];
            ax += lof(v0) + lof(v1);
            ay += hif(v0) + hif(v1);
        }
        if (k < end) {
            const unsigned v = H2[eid[k] * 32 + c2];
            ax += lof(v); ay += hif(v);
        }
    }
    ax += __shfl(ax, lane + 20, 64) + __shfl(ax, lane + 40, 64);
    ay += __shfl(ay, lane + 20, 64) + __shfl(ay, lane + 40, 64);

    const bool act = (lane < 20);
    float2 b = {0.f, 0.f};
    if (act) b = ((const float2*)b2)[lane];
    const float vx = ax + b.x, vy = ay + b.y;
    float m = act ? fmaxf(vx, vy) : -INFINITY;
#pragma unroll
    for (int off = 32; off; off >>= 1) m = fmaxf(m, __shfl_xor(m, off, 64));
    float e = act ? (expf(vx - m) + expf(vy - m)) : 0.f;
#pragma unroll
    for (int off = 32; off; off >>= 1) e += __shfl_xor(e, off, 64);
    const float ls = logf(e);
    if (act) {
        float2 o = {vx - m - ls, vy - m - ls};
        ((float2*)out)[n * 20 + lane] = o;
    }
}

extern "C" void kernel_launch(void* const* d_in, const int* in_sizes, int n_in,
                              void* d_out, int out_size, void* d_ws, size_t ws_size,
                              hipStream_t stream) {
    const float* x  = (const float*)d_in[0];
    const int*   ei = (const int*)d_in[1];   // [2, NE]: src then dst
    const float* W1 = (const float*)d_in[2];
    const float* b1 = (const float*)d_in[3];
    const float* W2 = (const float*)d_in[4];
    const float* b2 = (const float*)d_in[5];
    const int* src = ei;
    const int* dst = ei + NE;

    unsigned* H1   = (unsigned*)d_ws;                  // NN*64 (bf16x2)
    unsigned* h    = H1 + (size_t)NN * 64;             // NN*64 (bf16x2); binned aliases
    unsigned* H2   = h + (size_t)NN * 64;              // NN*32 (padded bf16x2)
    unsigned* W1T  = H2 + (size_t)NN * 32;             // 8192
    unsigned* W2T  = W1T + 8192;                       // 3072
    int* mat       = (int*)(W2T + 3072);               // MATN
    int* bucketoff = mat + MATN;                       // NBKT+1
    int* rowoff    = bucketoff + NBKT + 1;             // NN+1
    int* eid       = rowoff + NN + 1;                  // NE
    uint2* binned  = (uint2*)h;                        // NE uint2 (6.4MB <= 12.8MB of h)
    float* out     = (float*)d_out;

    binhist_k<<<NB_BIN, 256, 0, stream>>>(dst, mat, W1, W2, W1T, W2T);
    binscatter_k<<<NB_BIN, 256, 0, stream>>>(src, dst, mat, binned, bucketoff);
    bucketcsr_k<<<NBKT, 256, 0, stream>>>(binned, bucketoff, rowoff, eid);
    gemm1_k<<<512, 256, 0, stream>>>(x, W1T, (unsigned short*)H1);
    gather1_k<<<12500, 256, 0, stream>>>((const uint2*)H1, rowoff, eid, b1, (uint2*)h);
    gemm2_k<<<512, 256, 0, stream>>>(h, W2T, (unsigned short*)H2);
    gather2_k<<<12500, 256, 0, stream>>>(H2, rowoff, eid, b2, out);
}

// Round 8
// 121.892 us; speedup vs baseline: 2.3554x; 1.0634x over previous
//
#include <hip/hip_runtime.h>

#define NN 50000
#define NE 800000
#define NBKT 196      // dst>>8 buckets: 196*256 = 50176 >= NN
#define NB_BIN 128    // blocks in binning kernels
#define EPB (NE / NB_BIN)          // 6250 edges per bin block
#define MATN (NBKT * NB_BIN)       // 25088 = 256*98

using short8 = __attribute__((ext_vector_type(8))) short;
using f32x4  = __attribute__((ext_vector_type(4))) float;
union U4S8 { uint4 u; short8 v; };

// ---- bf16 helpers (RNE, f32 accumulate everywhere) ----
__device__ __forceinline__ float lof(unsigned v) { return __uint_as_float(v << 16); }
__device__ __forceinline__ float hif(unsigned v) { return __uint_as_float(v & 0xffff0000u); }
__device__ __forceinline__ unsigned bf16rne(float f) {
    unsigned u = __float_as_uint(f);
    return (u + 0x7fffu + ((u >> 16) & 1u)) >> 16;
}
__device__ __forceinline__ unsigned pack2(float a, float b) {
    return bf16rne(a) | (bf16rne(b) << 16);
}
// ---- fp8 e4m3 helpers: 4 f32 -> packed uint (bytes a0,a1,a2,a3), and unpack ----
__device__ __forceinline__ unsigned fp8pack4(float a0, float a1, float a2, float a3) {
    int w = __builtin_amdgcn_cvt_pk_fp8_f32(a0, a1, 0, false);
    w = __builtin_amdgcn_cvt_pk_fp8_f32(a2, a3, w, true);
    return (unsigned)w;
}

// ---------------- K1: per-block bucket histogram (+ weight bf16 pack) ----------------
// W1T[n][k]: k = real channel. W2T[n][q]: q = PERMUTED position, ch(q) = (q&7)*16 + (q>>3)
// (matches H1/h fp8 position layout p = (ch&15)*8 + (ch>>4)).
__global__ __launch_bounds__(256) void binhist_k(const int* __restrict__ dst,
                                                 int* __restrict__ mat,
                                                 const float* __restrict__ W1,
                                                 const float* __restrict__ W2,
                                                 unsigned* __restrict__ W1T,
                                                 unsigned* __restrict__ W2T) {
    __shared__ int hist[NBKT];
    const int tid = threadIdx.x;
    for (int i = tid; i < NBKT; i += 256) hist[i] = 0;

    const int g = blockIdx.x * 256 + tid;
    if (g < 8192) {
        const int n = g >> 6, k2 = (g & 63) * 2;
        W1T[g] = pack2(W1[k2 * 128 + n], W1[(k2 + 1) * 128 + n]);
    } else if (g < 8192 + 3072) {
        const int u = g - 8192;
        const int n = u >> 6;
        const int q0 = (u & 63) * 2, q1 = q0 + 1;
        const int c0 = (q0 & 7) * 16 + (q0 >> 3);
        const int c1 = (q1 & 7) * 16 + (q1 >> 3);
        W2T[u] = (n < 40) ? pack2(W2[c0 * 40 + n], W2[c1 * 40 + n]) : 0u;
    }
    __syncthreads();

    const int base = blockIdx.x * EPB;
    for (int e = base + tid; e < base + EPB; e += 256)
        atomicAdd(&hist[dst[e] >> 8], 1);
    __syncthreads();
    for (int i = tid; i < NBKT; i += 256)
        mat[i * NB_BIN + blockIdx.x] = hist[i];
}

// ---------------- K2: scatter into bucket order; each block scans mat in LDS ----------------
__global__ __launch_bounds__(256) void binscatter_k(const int* __restrict__ src,
                                                    const int* __restrict__ dst,
                                                    const int* __restrict__ mat,
                                                    unsigned* __restrict__ binned,
                                                    int* __restrict__ bucketoff) {
    __shared__ int lds[MATN];   // 100 KB
    __shared__ int tsum[256];
    const int tid = threadIdx.x;
    for (int i = tid; i < MATN; i += 256) lds[i] = mat[i];
    __syncthreads();
    const int b0 = tid * (MATN / 256);   // 98 each, exact
    int s = 0;
#pragma unroll 7
    for (int i = 0; i < MATN / 256; ++i) s += lds[b0 + i];
    tsum[tid] = s;
    __syncthreads();
#pragma unroll
    for (int off = 1; off < 256; off <<= 1) {
        int u = (tid >= off) ? tsum[tid - off] : 0;
        __syncthreads();
        tsum[tid] += u;
        __syncthreads();
    }
    int run = tsum[tid] - s;
#pragma unroll 7
    for (int i = 0; i < MATN / 256; ++i) {
        const int v = lds[b0 + i]; lds[b0 + i] = run; run += v;
    }
    __syncthreads();

    if (blockIdx.x == 0) {
        for (int i = tid; i < NBKT; i += 256) bucketoff[i] = lds[i * NB_BIN];
        if (tid == 0) bucketoff[NBKT] = NE;
        __syncthreads();
    }

    const int base = blockIdx.x * EPB;
    for (int e = base + tid; e < base + EPB; e += 256) {
        const int d = dst[e];
        const int p = atomicAdd(&lds[(d >> 8) * NB_BIN + blockIdx.x], 1);
        binned[p] = ((unsigned)(d & 255) << 16) | (unsigned)src[e];
    }
}

// ---------------- K3: per-bucket CSR (rowoff + ushort eid) ----------------
__global__ __launch_bounds__(256) void bucketcsr_k(const unsigned* __restrict__ binned,
                                                   const int* __restrict__ bucketoff,
                                                   int* __restrict__ rowoff,
                                                   unsigned short* __restrict__ eid) {
    __shared__ int cnt[256];
    __shared__ int off[256];
    const int b = blockIdx.x;
    const int tid = threadIdx.x;
    const int beg = bucketoff[b];
    const int end = bucketoff[b + 1];
    cnt[tid] = 0;
    __syncthreads();
    for (int i = beg + tid; i < end; i += 256)
        atomicAdd(&cnt[(binned[i] >> 16) & 255u], 1);
    __syncthreads();
    const int v = cnt[tid];
    off[tid] = v;
    __syncthreads();
#pragma unroll
    for (int o = 1; o < 256; o <<= 1) {
        int u = (tid >= o) ? off[tid - o] : 0;
        __syncthreads();
        off[tid] += u;
        __syncthreads();
    }
    const int excl = off[tid] - v;
    const int node = b * 256 + tid;
    if (node <= NN) rowoff[node] = beg + excl;
    cnt[tid] = excl;   // cursor
    __syncthreads();
    for (int i = beg + tid; i < end; i += 256) {
        const unsigned e = binned[i];
        const int p = atomicAdd(&cnt[(e >> 16) & 255u], 1);
        eid[beg + p] = (unsigned short)(e & 0xffffu);
    }
}

// ---------------- GEMM1 (MFMA): H1[50000] fp8, position-permuted rows of 128 B ----------------
// position p = (ch&15)*8 + (ch>>4); lane (cl,kh) owns p = cl*8+c for row kh*4+j -> uint2 store.
__global__ __launch_bounds__(256) void gemm1_k(const float* __restrict__ x,
                                               const unsigned* __restrict__ W1T,
                                               uint2* __restrict__ H1) {
    const int lane = threadIdx.x & 63;
    const int cl = lane & 15;
    const int kh = lane >> 4;   // 0..3
    const int gw = (blockIdx.x * 256 + threadIdx.x) >> 6;   // 0..2047

    short8 Bf[8][4];
#pragma unroll
    for (int c = 0; c < 8; ++c)
#pragma unroll
        for (int kc = 0; kc < 4; ++kc) {
            U4S8 tb;
            tb.u = *(const uint4*)(W1T + ((c * 16 + cl) * 128 + kc * 32 + kh * 8) / 2);
            Bf[c][kc] = tb.v;
        }

    for (int mt = gw; mt < 3125; mt += 2048) {
        const int r0 = mt * 16;
        const float* ap = x + (long)(r0 + cl) * 128 + kh * 8;
        f32x4 acc[8];
#pragma unroll
        for (int c = 0; c < 8; ++c) acc[c] = (f32x4){0.f, 0.f, 0.f, 0.f};
#pragma unroll
        for (int kc = 0; kc < 4; ++kc) {
            const float4 p0 = *(const float4*)(ap + kc * 32);
            const float4 p1 = *(const float4*)(ap + kc * 32 + 4);
            U4S8 af;
            af.u.x = pack2(p0.x, p0.y);
            af.u.y = pack2(p0.z, p0.w);
            af.u.z = pack2(p1.x, p1.y);
            af.u.w = pack2(p1.z, p1.w);
#pragma unroll
            for (int c = 0; c < 8; ++c)
                acc[c] = __builtin_amdgcn_mfma_f32_16x16x32_bf16(af.v, Bf[c][kc], acc[c], 0, 0, 0);
        }
#pragma unroll
        for (int j = 0; j < 4; ++j) {
            uint2 o;
            o.x = fp8pack4(acc[0][j], acc[1][j], acc[2][j], acc[3][j]);
            o.y = fp8pack4(acc[4][j], acc[5][j], acc[6][j], acc[7][j]);
            H1[(long)(r0 + kh * 4 + j) * 16 + cl] = o;   // 16 lanes x 8B = full 128B row
        }
    }
}

// ---------------- gather1 + bias + relu: h[n](bf16, position layout) ----------------
// one wave per node: 4 edge-slots x 16 lanes x uint2 (8 fp8 positions per lane)
__global__ __launch_bounds__(256) void gather1_k(const uint2* __restrict__ H1,
                                                 const int* __restrict__ rowoff,
                                                 const unsigned short* __restrict__ eid,
                                                 const float* __restrict__ b1,
                                                 uint4* __restrict__ h) {
    const int n = blockIdx.x * 4 + (threadIdx.x >> 6);
    const int lane = threadIdx.x & 63;
    const int g = lane >> 4;      // edge slot 0..3
    const int cl = lane & 15;     // uint2 column
    const int beg = rowoff[n], end = rowoff[n + 1];
    float a[8] = {0.f, 0.f, 0.f, 0.f, 0.f, 0.f, 0.f, 0.f};

#define ACC8(v)                                                              \
    {                                                                        \
        auto t0 = __builtin_amdgcn_cvt_pk_f32_fp8((int)(v).x, false);        \
        auto t1 = __builtin_amdgcn_cvt_pk_f32_fp8((int)(v).x, true);         \
        auto t2 = __builtin_amdgcn_cvt_pk_f32_fp8((int)(v).y, false);        \
        auto t3 = __builtin_amdgcn_cvt_pk_f32_fp8((int)(v).y, true);         \
        a[0] += t0[0]; a[1] += t0[1]; a[2] += t1[0]; a[3] += t1[1];          \
        a[4] += t2[0]; a[5] += t2[1]; a[6] += t3[0]; a[7] += t3[1];          \
    }

    int k = beg;
    for (; k + 7 < end; k += 8) {
        const int sA = eid[k + g];
        const int sB = eid[k + 4 + g];
        const uint2 vA = H1[sA * 16 + cl];
        const uint2 vB = H1[sB * 16 + cl];
        ACC8(vA);
        ACC8(vB);
    }
    for (; k + 3 < end; k += 4) {
        const uint2 v = H1[eid[k + g] * 16 + cl];
        ACC8(v);
    }
    if (k + g < end) {
        const uint2 v = H1[eid[k + g] * 16 + cl];
        ACC8(v);
    }
#undef ACC8

#pragma unroll
    for (int i = 0; i < 8; ++i) {
        a[i] += __shfl_xor(a[i], 16, 64);
        a[i] += __shfl_xor(a[i], 32, 64);
    }
    if (lane < 16) {   // position p = cl*8+i -> channel i*16+cl
        float r[8];
#pragma unroll
        for (int i = 0; i < 8; ++i) r[i] = fmaxf(a[i] + b1[i * 16 + cl], 0.f);
        uint4 o;
        o.x = pack2(r[0], r[1]);
        o.y = pack2(r[2], r[3]);
        o.z = pack2(r[4], r[5]);
        o.w = pack2(r[6], r[7]);
        h[n * 16 + cl] = o;   // 16 lanes x 16B = 256B row
    }
}

// ---------------- GEMM2 (MFMA): H2[50000, pad 64](bf16) = h(bf16, pos layout) @ W2T(pos k) ----------------
__global__ __launch_bounds__(256) void gemm2_k(const unsigned* __restrict__ h,
                                               const unsigned* __restrict__ W2T,
                                               unsigned short* __restrict__ H2) {
    const int lane = threadIdx.x & 63;
    const int cl = lane & 15;
    const int kh = lane >> 4;
    const int gw = (blockIdx.x * 256 + threadIdx.x) >> 6;

    short8 Bf[3][4];
#pragma unroll
    for (int c = 0; c < 3; ++c)
#pragma unroll
        for (int kc = 0; kc < 4; ++kc) {
            U4S8 tb;
            tb.u = *(const uint4*)(W2T + ((c * 16 + cl) * 128 + kc * 32 + kh * 8) / 2);
            Bf[c][kc] = tb.v;
        }

    for (int mt = gw; mt < 3125; mt += 2048) {
        const int r0 = mt * 16;
        const unsigned* ap = h + (long)(r0 + cl) * 64 + kh * 4;
        f32x4 acc[3];
#pragma unroll
        for (int c = 0; c < 3; ++c) acc[c] = (f32x4){0.f, 0.f, 0.f, 0.f};
#pragma unroll
        for (int kc = 0; kc < 4; ++kc) {
            U4S8 af;
            af.u = *(const uint4*)(ap + kc * 16);
#pragma unroll
            for (int c = 0; c < 3; ++c)
                acc[c] = __builtin_amdgcn_mfma_f32_16x16x32_bf16(af.v, Bf[c][kc], acc[c], 0, 0, 0);
        }
        unsigned short* hp = H2 + (long)(r0 + kh * 4) * 64;
#pragma unroll
        for (int c = 0; c < 3; ++c) {
            const int col = c * 16 + cl;
            if (col < 40) {
#pragma unroll
                for (int j = 0; j < 4; ++j)
                    hp[j * 64 + col] = (unsigned short)bf16rne(acc[c][j]);
            }
        }
    }
}

// ---------------- gather2 + bias + log_softmax (H2 row stride 32 uints) ----------------
__global__ __launch_bounds__(256) void gather2_k(const unsigned* __restrict__ H2,
                                                 const int* __restrict__ rowoff,
                                                 const unsigned short* __restrict__ eid,
                                                 const float* __restrict__ b2,
                                                 float* __restrict__ out) {
    const int n = blockIdx.x * 4 + (threadIdx.x >> 6);
    const int lane = threadIdx.x & 63;
    const int g = lane / 20;        // edge-group 0..2 (g==3 idle)
    const int c2 = lane - g * 20;   // channel-pair 0..19
    const int beg = rowoff[n], end = rowoff[n + 1];
    float ax = 0.f, ay = 0.f;
    if (g < 3) {
        int k = beg + g;
        for (; k + 3 < end; k += 6) {
            const int s0 = eid[k], s1 = eid[k + 3];
            const unsigned v0 = H2[s0 * 32 + c2];
            const unsigned v1 = H2[s1 * 32 + c2];
            ax += lof(v0) + lof(v1);
            ay += hif(v0) + hif(v1);
        }
        if (k < end) {
            const unsigned v = H2[eid[k] * 32 + c2];
            ax += lof(v); ay += hif(v);
        }
    }
    ax += __shfl(ax, lane + 20, 64) + __shfl(ax, lane + 40, 64);
    ay += __shfl(ay, lane + 20, 64) + __shfl(ay, lane + 40, 64);

    const bool act = (lane < 20);
    float2 b = {0.f, 0.f};
    if (act) b = ((const float2*)b2)[lane];
    const float vx = ax + b.x, vy = ay + b.y;
    float m = act ? fmaxf(vx, vy) : -INFINITY;
#pragma unroll
    for (int off = 32; off; off >>= 1) m = fmaxf(m, __shfl_xor(m, off, 64));
    float e = act ? (expf(vx - m) + expf(vy - m)) : 0.f;
#pragma unroll
    for (int off = 32; off; off >>= 1) e += __shfl_xor(e, off, 64);
    const float ls = logf(e);
    if (act) {
        float2 o = {vx - m - ls, vy - m - ls};
        ((float2*)out)[n * 20 + lane] = o;
    }
}

extern "C" void kernel_launch(void* const* d_in, const int* in_sizes, int n_in,
                              void* d_out, int out_size, void* d_ws, size_t ws_size,
                              hipStream_t stream) {
    const float* x  = (const float*)d_in[0];
    const int*   ei = (const int*)d_in[1];   // [2, NE]: src then dst
    const float* W1 = (const float*)d_in[2];
    const float* b1 = (const float*)d_in[3];
    const float* W2 = (const float*)d_in[4];
    const float* b2 = (const float*)d_in[5];
    const int* src = ei;
    const int* dst = ei + NE;

    unsigned* H1   = (unsigned*)d_ws;                  // NN*32 (fp8 rows, 128B)
    unsigned* h    = H1 + (size_t)NN * 32;             // NN*64 (bf16x2, pos layout); binned aliases
    unsigned* H2   = h + (size_t)NN * 64;              // NN*32 (padded bf16x2)
    unsigned* W1T  = H2 + (size_t)NN * 32;             // 8192
    unsigned* W2T  = W1T + 8192;                       // 3072
    int* mat       = (int*)(W2T + 3072);               // MATN
    int* bucketoff = mat + MATN;                       // NBKT+1
    int* rowoff    = bucketoff + NBKT + 1;             // NN+1
    unsigned short* eid = (unsigned short*)(rowoff + NN + 1);  // NE ushort
    unsigned* binned = h;                              // NE uint (3.2MB <= 12.8MB of h)
    float* out     = (float*)d_out;

    binhist_k<<<NB_BIN, 256, 0, stream>>>(dst, mat, W1, W2, W1T, W2T);
    binscatter_k<<<NB_BIN, 256, 0, stream>>>(src, dst, mat, binned, bucketoff);
    bucketcsr_k<<<NBKT, 256, 0, stream>>>(binned, bucketoff, rowoff, eid);
    gemm1_k<<<512, 256, 0, stream>>>(x, W1T, (uint2*)H1);
    gather1_k<<<12500, 256, 0, stream>>>((const uint2*)H1, rowoff, eid, b1, (uint4*)h);
    gemm2_k<<<512, 256, 0, stream>>>(h, W2T, (unsigned short*)H2);
    gather2_k<<<12500, 256, 0, stream>>>(H2, rowoff, eid, b2, out);
}